// Round 7
// baseline (237.582 us; speedup 1.0000x reference)
//
#include <hip/hip_runtime.h>
#include <hip/hip_bf16.h>

// Problem constants (from reference setup_inputs): emission [B, T, V] float32
#define CTC_B 64
#define CTC_T 8192
#define CTC_V 32
#define BLANK 0

#define TPB 256
#define NBLK (CTC_B * CTC_T * 4 / TPB)   // 8192 blocks: 4 lanes/row, 64 rows/blk

typedef float f32x4 __attribute__((ext_vector_type(4)));
typedef unsigned long long ull;
typedef ull ullx2 __attribute__((ext_vector_type(2)));

// ---------------------------------------------------------------------------
// SWAR: high bit of each byte set iff that byte of x is nonzero.
// ---------------------------------------------------------------------------
__device__ __forceinline__ ull nzmask(ull x) {
    return (x | ((x & 0x7f7f7f7f7f7f7f7fULL) + 0x7f7f7f7f7f7f7f7fULL))
           & 0x8080808080808080ULL;
}

// OR the "differs from left neighbor" high-bit mask of 32 columns [c0,c0+32)
// of batch row rb into hk[0..3].
__device__ __forceinline__ void colkeep_row(const unsigned char* __restrict__ rb,
                                            int c0, ull hk[4]) {
    ullx2 lo = *reinterpret_cast<const ullx2*>(rb + c0);
    ullx2 hi = *reinterpret_cast<const ullx2*>(rb + c0 + 16);
    ull x0 = lo.x, x1 = lo.y, x2 = hi.x, x3 = hi.y;
    ull carry = (c0 == 0) ? 0ULL : (ull)rb[c0 - 1];
    hk[0] |= nzmask(x0 ^ ((x0 << 8) | carry));
    hk[1] |= nzmask(x1 ^ ((x1 << 8) | (x0 >> 56)));
    hk[2] |= nzmask(x2 ^ ((x2 << 8) | (x1 >> 56)));
    hk[3] |= nzmask(x3 ^ ((x3 << 8) | (x2 >> 56)));
}

// ---------------------------------------------------------------------------
// Single fused kernel, PLAIN launch (no cooperative).
// Phase 1 (all 8192 blocks, 256 thr): R4's exact argmax — 4 lanes per (b,t)
//   row, float4-pair loads, 2 shuffle-reduce rounds, first-occurrence
//   tie-break. Full occupancy streaming, identical to the 21.4 µs version.
// Handshake: each block release-adds 1 to *cnt after its slice is stored.
// Phase 2 (blocks 0..63): acquire-spin until cnt==NBLK, then single-pass
//   colkeep+compact of batch row b=blockIdx (same algorithm as R4, re-tiled
//   for 256 threads: 32 columns per thread).
// ---------------------------------------------------------------------------
__global__ __launch_bounds__(TPB) void ctc_fused_kernel(
    const float* __restrict__ em, unsigned char* __restrict__ idx,
    int* __restrict__ btokens, int* __restrict__ lens, int* __restrict__ cnt) {

    // ---------------- phase 1: argmax (R4-exact) ----------------
    {
        const int tid = blockIdx.x * TPB + threadIdx.x;   // 4 threads per row
        const int row = tid >> 2;
        const int sub = tid & 3;
        const f32x4* p = reinterpret_cast<const f32x4*>(em) + (size_t)row * 8 + sub;
        f32x4 a = p[0];   // elements 4*sub   .. 4*sub+3
        f32x4 b = p[4];   // elements 16+4*sub .. 16+4*sub+3
        const int i1 = sub * 4, i2 = 16 + sub * 4;

        float best = a.x; int bi = i1;
        if (a.y > best) { best = a.y; bi = i1 + 1; }
        if (a.z > best) { best = a.z; bi = i1 + 2; }
        if (a.w > best) { best = a.w; bi = i1 + 3; }
        if (b.x > best) { best = b.x; bi = i2;     }
        if (b.y > best) { best = b.y; bi = i2 + 1; }
        if (b.z > best) { best = b.z; bi = i2 + 2; }
        if (b.w > best) { best = b.w; bi = i2 + 3; }

#pragma unroll
        for (int m = 1; m < 4; m <<= 1) {
            float ob = __shfl_xor(best, m, 64);
            int   oi = __shfl_xor(bi,   m, 64);
            if (ob > best || (ob == best && oi < bi)) { best = ob; bi = oi; }
        }
        if (sub == 0) idx[row] = (unsigned char)bi;
    }

    // ---------------- handshake ----------------
    __syncthreads();   // drains this block's idx stores (vmcnt(0) at barrier)
    if (threadIdx.x == 0) {
        // release: makes this block's stores visible at agent scope
        __hip_atomic_fetch_add(cnt, 1, __ATOMIC_RELEASE, __HIP_MEMORY_SCOPE_AGENT);
    }
    if (blockIdx.x >= CTC_B) return;

    // winners (blocks 0..63): wait until ALL blocks have signalled
    if (threadIdx.x == 0) {
        while (__hip_atomic_load(cnt, __ATOMIC_ACQUIRE, __HIP_MEMORY_SCOPE_AGENT)
               < NBLK) {
            __builtin_amdgcn_s_sleep(4);
        }
    }
    __syncthreads();   // broadcast thread0's acquired view to the block

    // ---------------- phase 2: colkeep + compact, row b = blockIdx ---------
    const int b   = blockIdx.x;
    const int tid = threadIdx.x;
    const int c0  = tid * 32;                    // first column this thread owns
    const unsigned char* row = idx + (size_t)b * CTC_T;
    int* orow = btokens + (size_t)b * CTC_T;

    __shared__ int s_wsum[4];
    const int lane = tid & 63;
    const int wid  = tid >> 6;
    const ull H = 0x8080808080808080ULL;

    // colkeep over batch rows 0,1 branchless; rare loop while undecided
    ull hk[4] = {0ULL, 0ULL, 0ULL, 0ULL};
    colkeep_row(idx, c0, hk);                    // batch row 0
    colkeep_row(idx + CTC_T, c0, hk);            // batch row 1
    if (c0 == 0) hk[0] |= 0x80ULL;               // col_keep[0] = 1 always

    for (int bb = 2; bb < CTC_B; ++bb) {
        if (((hk[0] & hk[1] & hk[2] & hk[3]) & H) == H) break;  // all decided
        colkeep_row(idx + (size_t)bb * CTC_T, c0, hk);
    }

    // own values + keep mask (BLANK==0 -> nonzero byte)
    ullx2 vlo = *reinterpret_cast<const ullx2*>(row + c0);
    ullx2 vhi = *reinterpret_cast<const ullx2*>(row + c0 + 16);
    ull xv[4] = {vlo.x, vlo.y, vhi.x, vhi.y};
    ull kp[4];
    int c = 0;
#pragma unroll
    for (int j = 0; j < 4; ++j) {
        kp[j] = hk[j] & nzmask(xv[j]);
        c += __popcll(kp[j]);
    }

    // block exclusive scan of per-thread counts (4 waves)
    int scan = c;
#pragma unroll
    for (int m = 1; m < 64; m <<= 1) {
        int o = __shfl_up(scan, m, 64);
        if (lane >= m) scan += o;
    }
    if (lane == 63) s_wsum[wid] = scan;
    __syncthreads();

    int woff = 0, total = 0;
#pragma unroll
    for (int w = 0; w < 4; ++w) {
        int x = s_wsum[w];
        if (w < wid) woff += x;
        total += x;
    }
    int pos = woff + (scan - c);                 // global exclusive prefix

    // scatter kept tokens (consecutive per thread)
#pragma unroll
    for (int j = 0; j < 4; ++j) {
        ull k = kp[j], x = xv[j];
#pragma unroll
        for (int by = 0; by < 8; ++by) {
            if (k & (0x80ULL << (8 * by))) {
                orow[pos++] = (int)((x >> (8 * by)) & 0xffULL);
            }
        }
    }

    // tail zero-fill (int4-vectorized) + lens
    int vstart = (total + 3) & ~3;               // 16B-aligned fill start
    if (tid < vstart - total) orow[total + tid] = BLANK;
    int4* vout = reinterpret_cast<int4*>(orow + vstart);
    const int nvec = (CTC_T - vstart) >> 2;
    const int4 z = make_int4(BLANK, BLANK, BLANK, BLANK);
    for (int i = tid; i < nvec; i += TPB) vout[i] = z;
    if (tid == 0) lens[b] = total;
}

// ---------------------------------------------------------------------------
extern "C" void kernel_launch(void* const* d_in, const int* in_sizes, int n_in,
                              void* d_out, int out_size, void* d_ws, size_t ws_size,
                              hipStream_t stream) {
    const float* emission = (const float*)d_in[0];
    int* out = (int*)d_out;                 // [B*T btokens][B lens], int32
    int* btokens = out;
    int* lens = out + (size_t)CTC_B * CTC_T;

    unsigned char* idx = (unsigned char*)d_ws;                       // B*T bytes
    int* cnt = (int*)((char*)d_ws + (size_t)CTC_B * CTC_T);          // 4 bytes

    hipMemsetAsync(cnt, 0, sizeof(int), stream);   // capture-safe, per-call
    ctc_fused_kernel<<<NBLK, TPB, 0, stream>>>(emission, idx, btokens, lens, cnt);
}

// Round 8
// 21.250 us; speedup vs baseline: 11.1802x; 11.1802x over previous
//
#include <hip/hip_runtime.h>
#include <hip/hip_bf16.h>

// Problem constants (from reference setup_inputs): emission [B, T, V] float32
#define CTC_B 64
#define CTC_T 8192
#define CTC_V 32
#define BLANK 0

// ---------------------------------------------------------------------------
// Kernel 1: argmax over labels. 4 lanes per (b,t) row; each lane loads TWO
// independent float4s (elements [4s,4s+4) and [16+4s,16+4s+4)) -> 2-deep load
// ILP, 16 rows per wave, only 2 shuffle-reduce rounds.
// First-occurrence tie-break: in-lane indices are ascending with strict '>',
// cross-lane reduce prefers the smaller index on exact float equality.
// (R5/R6/R7 variants — fewer waves, NT loads, coop fusion, spin fusion — all
//  measured neutral or regressed; this shape is the empirical optimum.)
// ---------------------------------------------------------------------------
__global__ __launch_bounds__(256) void ctc_argmax_kernel(
    const float* __restrict__ em, unsigned char* __restrict__ idx) {
    int tid = blockIdx.x * blockDim.x + threadIdx.x;   // 4 threads per row
    int row = tid >> 2;
    int sub = tid & 3;
    const float4* p = reinterpret_cast<const float4*>(em) + (size_t)row * 8 + sub;
    float4 a = p[0];   // covers elements 4*sub   .. 4*sub+3
    float4 b = p[4];   // covers elements 16+4*sub .. 16+4*sub+3
    const int b1 = sub * 4, b2 = 16 + sub * 4;

    float best = a.x; int bi = b1;
    if (a.y > best) { best = a.y; bi = b1 + 1; }
    if (a.z > best) { best = a.z; bi = b1 + 2; }
    if (a.w > best) { best = a.w; bi = b1 + 3; }
    if (b.x > best) { best = b.x; bi = b2;     }
    if (b.y > best) { best = b.y; bi = b2 + 1; }
    if (b.z > best) { best = b.z; bi = b2 + 2; }
    if (b.w > best) { best = b.w; bi = b2 + 3; }

    // reduce across the 4-lane group (xor masks 1,2 stay in-group)
#pragma unroll
    for (int m = 1; m < 4; m <<= 1) {
        float ob = __shfl_xor(best, m, 64);
        int   oi = __shfl_xor(bi,   m, 64);
        if (ob > best || (ob == best && oi < bi)) { best = ob; bi = oi; }
    }
    if (sub == 0) idx[row] = (unsigned char)bi;   // 16 consecutive bytes/wave
}

// ---------------------------------------------------------------------------
// SWAR: high bit of each byte set iff that byte of x is nonzero.
// ---------------------------------------------------------------------------
__device__ __forceinline__ unsigned long long nzmask(unsigned long long x) {
    return (x | ((x & 0x7f7f7f7f7f7f7f7fULL) + 0x7f7f7f7f7f7f7f7fULL))
           & 0x8080808080808080ULL;
}

// ---------------------------------------------------------------------------
// Kernel 2 (fused colkeep + compact): one block of 1024 threads per batch
// row; each thread owns 8 CONSECUTIVE columns (one u64 byte-vector). Single
// pass, single barrier:
//   colkeep: SWAR compare of column t vs t-1 for batch rows 0,1 branchless,
//            rare loop over rows 2..63 only while some byte is undecided.
//   scan:    per-thread popcount -> wave shfl_up scan -> 16-int LDS -> barrier
//   scatter: <=8 consecutive int stores per thread + vectorized tail fill.
// ---------------------------------------------------------------------------
__global__ __launch_bounds__(1024) void ctc_compact_kernel(
    const unsigned char* __restrict__ idx,
    int* __restrict__ btokens, int* __restrict__ lens) {
    const int b   = blockIdx.x;
    const int tid = threadIdx.x;
    const int t8  = tid * 8;                     // first column this thread owns
    const unsigned char* row = idx + (size_t)b * CTC_T;
    int* orow = btokens + (size_t)b * CTC_T;

    __shared__ int s_wsum[16];
    const int lane = tid & 63;
    const int wid  = tid >> 6;

    // --- load own 8 values + boundary byte, and dedup rows 0,1 ---
    const unsigned long long xv = *reinterpret_cast<const unsigned long long*>(row + t8);
    const unsigned char* r0 = idx;               // batch row 0
    const unsigned char* r1 = idx + CTC_T;       // batch row 1
    unsigned long long x0 = *reinterpret_cast<const unsigned long long*>(r0 + t8);
    unsigned long long x1 = *reinterpret_cast<const unsigned long long*>(r1 + t8);
    unsigned char p0 = (t8 == 0) ? (unsigned char)0 : r0[t8 - 1];
    unsigned char p1 = (t8 == 0) ? (unsigned char)0 : r1[t8 - 1];

    // colkeep high-bit mask: byte j <-> column t8+j ; prev column = byte j-1
    unsigned long long hk = nzmask(x0 ^ ((x0 << 8) | (unsigned long long)p0))
                          | nzmask(x1 ^ ((x1 << 8) | (unsigned long long)p1));
    if (t8 == 0) hk |= 0x80ULL;                  // col_keep[0] = 1 always

    unsigned long long und = ~hk & 0x8080808080808080ULL;
    for (int bb = 2; bb < CTC_B && und; ++bb) {
        const unsigned char* rb = idx + (size_t)bb * CTC_T;
        unsigned long long xb = *reinterpret_cast<const unsigned long long*>(rb + t8);
        unsigned char pb = (t8 == 0) ? (unsigned char)0 : rb[t8 - 1];
        hk |= nzmask(xb ^ ((xb << 8) | (unsigned long long)pb));
        und = ~hk & 0x8080808080808080ULL;
    }

    // keep = col_keep & (value != BLANK)   (BLANK==0 -> nonzero byte)
    const unsigned long long keep_hi = hk & nzmask(xv);
    const int c = __popcll(keep_hi);

    // --- block exclusive scan of per-thread counts ---
    int scan = c;
#pragma unroll
    for (int m = 1; m < 64; m <<= 1) {
        int o = __shfl_up(scan, m, 64);
        if (lane >= m) scan += o;
    }
    if (lane == 63) s_wsum[wid] = scan;          // wave total (inclusive of last)
    __syncthreads();

    int woff = 0, total = 0;
#pragma unroll
    for (int w = 0; w < 16; ++w) {
        int x = s_wsum[w];
        if (w < wid) woff += x;
        total += x;
    }
    int pos = woff + (scan - c);                 // global exclusive prefix

    // --- scatter kept tokens (consecutive per thread) ---
#pragma unroll
    for (int j = 0; j < 8; ++j) {
        if (keep_hi & (0x80ULL << (8 * j))) {
            orow[pos++] = (int)((xv >> (8 * j)) & 0xffULL);
        }
    }

    // --- tail zero-fill (int4-vectorized) + lens ---
    int vstart = (total + 3) & ~3;               // 16B-aligned fill start
    if (tid < vstart - total) orow[total + tid] = BLANK;
    int4* vout = reinterpret_cast<int4*>(orow + vstart);
    const int nvec = (CTC_T - vstart) >> 2;
    const int4 z = make_int4(BLANK, BLANK, BLANK, BLANK);
    for (int i = tid; i < nvec; i += 1024) vout[i] = z;
    if (tid == 0) lens[b] = total;
}

// ---------------------------------------------------------------------------
extern "C" void kernel_launch(void* const* d_in, const int* in_sizes, int n_in,
                              void* d_out, int out_size, void* d_ws, size_t ws_size,
                              hipStream_t stream) {
    const float* emission = (const float*)d_in[0];
    int* out = (int*)d_out;                 // [B*T btokens][B lens], int32
    int* btokens = out;
    int* lens = out + (size_t)CTC_B * CTC_T;

    unsigned char* idx = (unsigned char*)d_ws;   // B*T bytes

    const int total_threads = CTC_B * CTC_T * 4; // 4 lanes per row
    ctc_argmax_kernel<<<total_threads / 256, 256, 0, stream>>>(emission, idx);
    ctc_compact_kernel<<<CTC_B, 1024, 0, stream>>>(idx, btokens, lens);
}